// Round 13
// baseline (246.083 us; speedup 1.0000x reference)
//
#include <hip/hip_runtime.h>

#define N_NODES 100000
#define F_IN 512
#define HID 16
#define F_OUT 40

#define NB 784        // buckets = row >> 7
#define BSHIFT 7
#define ROWS_PB 128
#define BCAP 4608     // mean 4096 + 8 sigma
#define CUR_PAD 16    // gcursor stride in ints (64B line per counter)
#define APAD 17
#define PARTB 1024    // part1 blocks inside k_fat (256 threads each)

// ---------------- zero gcursor ----------------
__global__ void k_zero(int* __restrict__ g) {
    int i = blockIdx.x * 256 + threadIdx.x;
    if (i < NB * CUR_PAD) g[i] = 0;
}

// ---- FAT: blocks [0,PARTB) = edge bucket-scatter; rest = GEMM1 (raw Hs) ----
// GEMM: 128 rows/block, 4 wave-uniform K-chunks (128k), 2 rows per lane.
__global__ __launch_bounds__(256) void k_fat(const float* __restrict__ x,
                                             const float* __restrict__ W1,
                                             const int* __restrict__ ei, int E,
                                             int* __restrict__ gcursor,
                                             unsigned int* __restrict__ sortbuf,
                                             float* __restrict__ Hs) {
    __shared__ float smem[4 * 128 * APAD];   // 34.8 KB, unioned across paths
    int t = threadIdx.x;
    if (blockIdx.x < PARTB) {
        // ---------------- part1: bucket scatter (packed u32) ----------------
        int* lcnt = (int*)smem;         // NB
        int* gb   = lcnt + NB;          // NB
        int epb = (E + PARTB - 1) / PARTB;          // 3125
        int base = blockIdx.x * epb;
        int lim = min(base + epb, E);
        for (int cbase = base; cbase < lim; cbase += 4096) {
            int cend = min(cbase + 4096, lim);
            for (int i = t; i < NB; i += 256) lcnt[i] = 0;
            __syncthreads();
            unsigned int v[16]; int bkt[16], mi[16];
#pragma unroll
            for (int i = 0; i < 16; ++i) {
                int e = cbase + i * 256 + t;
                bkt[i] = -1;
                if (e < cend) {
                    int r = ei[e], c = ei[E + e];
                    bkt[i] = r >> BSHIFT;
                    v[i] = ((unsigned)(r & (ROWS_PB - 1)) << 17) | (unsigned)c;
                    mi[i] = atomicAdd(&lcnt[bkt[i]], 1);
                }
            }
            __syncthreads();
            for (int i = t; i < NB; i += 256)
                gb[i] = atomicAdd(&gcursor[i * CUR_PAD], lcnt[i]);
            __syncthreads();
#pragma unroll
            for (int i = 0; i < 16; ++i)
                if (bkt[i] >= 0) {
                    int idx = gb[bkt[i]] + mi[i];
                    if (idx < BCAP) sortbuf[(size_t)bkt[i] * BCAP + idx] = v[i];
                }
            __syncthreads();
        }
    } else {
        // -- GEMM1: 2 rows/lane share each s_load'd W1 value (halved chain) --
        float* red = smem;
        int kc = __builtin_amdgcn_readfirstlane(t >> 6);   // 0..3, s_load path
        int rl = t & 63;
        int bid = blockIdx.x - PARTB;
        int r0 = bid * 128 + rl;
        int r1 = r0 + 64;

        float acc0[HID], acc1[HID];
#pragma unroll
        for (int f = 0; f < HID; ++f) { acc0[f] = 0.0f; acc1[f] = 0.0f; }

        const float* wp = W1 + kc * 128 * HID;
        bool ok0 = r0 < N_NODES, ok1 = r1 < N_NODES;
        const float* xp0 = x + (size_t)(ok0 ? r0 : 0) * F_IN + kc * 128;
        const float* xp1 = x + (size_t)(ok1 ? r1 : 0) * F_IN + kc * 128;

        float4 a0 = *reinterpret_cast<const float4*>(xp0);
        float4 a1 = *reinterpret_cast<const float4*>(xp0 + 4);
        float4 a2 = *reinterpret_cast<const float4*>(xp0 + 8);
        float4 a3 = *reinterpret_cast<const float4*>(xp0 + 12);
        float4 b0 = *reinterpret_cast<const float4*>(xp1);
        float4 b1v = *reinterpret_cast<const float4*>(xp1 + 4);
        float4 b2v = *reinterpret_cast<const float4*>(xp1 + 8);
        float4 b3 = *reinterpret_cast<const float4*>(xp1 + 12);
        for (int k = 0; k < 128; k += 16) {
            float4 n0, n1, n2, n3, m0, m1, m2, m3;
            if (k + 16 < 128) {
                n0 = *reinterpret_cast<const float4*>(xp0 + k + 16);
                n1 = *reinterpret_cast<const float4*>(xp0 + k + 20);
                n2 = *reinterpret_cast<const float4*>(xp0 + k + 24);
                n3 = *reinterpret_cast<const float4*>(xp0 + k + 28);
                m0 = *reinterpret_cast<const float4*>(xp1 + k + 16);
                m1 = *reinterpret_cast<const float4*>(xp1 + k + 20);
                m2 = *reinterpret_cast<const float4*>(xp1 + k + 24);
                m3 = *reinterpret_cast<const float4*>(xp1 + k + 28);
            } else {
                n0 = a0; n1 = a1; n2 = a2; n3 = a3;
                m0 = b0; m1 = b1v; m2 = b2v; m3 = b3;
            }
            float xs0[16] = {a0.x, a0.y, a0.z, a0.w, a1.x, a1.y, a1.z, a1.w,
                             a2.x, a2.y, a2.z, a2.w, a3.x, a3.y, a3.z, a3.w};
            float xs1[16] = {b0.x, b0.y, b0.z, b0.w, b1v.x, b1v.y, b1v.z, b1v.w,
                             b2v.x, b2v.y, b2v.z, b2v.w, b3.x, b3.y, b3.z, b3.w};
#pragma unroll
            for (int kk = 0; kk < 16; ++kk) {
                float x0 = xs0[kk], x1 = xs1[kk];
#pragma unroll
                for (int f = 0; f < HID; ++f) {
                    float w = wp[(k + kk) * HID + f];   // s_load, shared by 2 rows
                    acc0[f] = fmaf(x0, w, acc0[f]);
                    acc1[f] = fmaf(x1, w, acc1[f]);
                }
            }
            a0 = n0; a1 = n1; a2 = n2; a3 = n3;
            b0 = m0; b1v = m1; b2v = m2; b3 = m3;
        }
        int base0 = (kc * 128 + rl) * APAD;
        int base1 = (kc * 128 + 64 + rl) * APAD;
#pragma unroll
        for (int f = 0; f < HID; ++f) { red[base0 + f] = acc0[f]; red[base1 + f] = acc1[f]; }
        __syncthreads();
#pragma unroll
        for (int p = 0; p < 8; ++p) {
            int o = p * 256 + t;                  // 0..2047 = 128 rows x 16 f
            int r = o >> 4, f = o & 15;
            int rg = bid * 128 + r;
            if (rg < N_NODES) {
                float s = 0.0f;
#pragma unroll
                for (int c = 0; c < 4; ++c) s += red[(c * 128 + r) * APAD + f];
                Hs[(size_t)rg * HID + f] = s;       // raw; scaled in k_build
            }
        }
    }
}

// -- build: bucket scan + LDS hist + scatter; fused dinv + Hs scaling ---------
__global__ __launch_bounds__(256) void k_build(const unsigned int* __restrict__ sortbuf,
                                               const int* __restrict__ gcursor,
                                               int* __restrict__ rowptr,
                                               float* __restrict__ dinv,
                                               int* __restrict__ colv,
                                               float* __restrict__ Hs) {
    __shared__ int bb[NB];
    __shared__ int s[256];
    __shared__ int hist[ROWS_PB];
    __shared__ int rstart[ROWS_PB];
    __shared__ int cur[ROWS_PB];
    __shared__ float sdinv[ROWS_PB];
    int b = blockIdx.x, t = threadIdx.x;

    // bucket-base scan (784 totals, 4/thread over 196 threads)
    int l0 = 0, l1 = 0, l2 = 0, l3 = 0;
    if (t < 196) {
        l0 = min(gcursor[(t * 4 + 0) * CUR_PAD], BCAP);
        l1 = min(gcursor[(t * 4 + 1) * CUR_PAD], BCAP);
        l2 = min(gcursor[(t * 4 + 2) * CUR_PAD], BCAP);
        l3 = min(gcursor[(t * 4 + 3) * CUR_PAD], BCAP);
    }
    int part = l0 + l1 + l2 + l3;
    s[t] = part;
    __syncthreads();
    for (int off = 1; off < 256; off <<= 1) {
        int a = (t >= off) ? s[t - off] : 0;
        __syncthreads();
        s[t] += a;
        __syncthreads();
    }
    if (t < 196) {
        int ex = s[t] - part;
        bb[t * 4 + 0] = ex;
        bb[t * 4 + 1] = ex + l0;
        bb[t * 4 + 2] = ex + l0 + l1;
        bb[t * 4 + 3] = ex + l0 + l1 + l2;
    }
    if (t < ROWS_PB) hist[t] = 0;
    __syncthreads();
    int gbase = bb[b];
    int n = min(gcursor[b * CUR_PAD], BCAP);
    if (b == 0 && t == 0) rowptr[N_NODES] = s[255];

    // per-row histogram
    const unsigned int* sb = sortbuf + (size_t)b * BCAP;
    for (int i = t; i < n; i += 256) atomicAdd(&hist[sb[i] >> 17], 1);
    __syncthreads();
    int c0 = (t < ROWS_PB) ? hist[t] : 0;
    s[t] = c0;
    __syncthreads();
    for (int off = 1; off < 256; off <<= 1) {
        int a = (t >= off) ? s[t - off] : 0;
        __syncthreads();
        s[t] += a;
        __syncthreads();
    }
    if (t < ROWS_PB) {
        int ex = s[t] - c0;
        rstart[t] = ex;
        cur[t] = 0;
        float dv = rsqrtf((float)(c0 + 1));   // +1 self-loop
        sdinv[t] = dv;
        int g = b * ROWS_PB + t;
        if (g < N_NODES) {
            rowptr[g] = gbase + ex;
            dinv[g] = dv;
        }
    }
    __syncthreads();
    // scatter into row-sorted colv
    for (int i = t; i < n; i += 256) {
        unsigned int v = sb[i];
        int lr = v >> 17;
        int pos = atomicAdd(&cur[lr], 1);
        colv[gbase + rstart[lr] + pos] = (int)(v & 0x1FFFFu);
    }
    __syncthreads();
    // scale this bucket's Hs rows: Hs *= dinv (gemm wrote raw)
    for (int i = t; i < ROWS_PB * 4; i += 256) {
        int row = i >> 2, q = i & 3;
        int g = b * ROWS_PB + row;
        if (g < N_NODES) {
            float4* p = reinterpret_cast<float4*>(Hs + (size_t)g * HID + q * 4);
            float4 vv = *p;
            float dv = sdinv[row];
            vv.x *= dv; vv.y *= dv; vv.z *= dv; vv.w *= dv;
            *p = vv;
        }
    }
}

// -- agg1: wave/node pull, float4 gathers, scalar-hoisted row meta ------------
__global__ __launch_bounds__(256) void k_agg1(const int* __restrict__ rowptr,
                                              const int* __restrict__ colv,
                                              const float* __restrict__ dinv,
                                              const float* __restrict__ Hs,
                                              const float* __restrict__ b1,
                                              float* __restrict__ h1s) {
    int wid = __builtin_amdgcn_readfirstlane((blockIdx.x * 256 + threadIdx.x) >> 6);
    if (wid >= N_NODES) return;
    int lane = threadIdx.x & 63;
    int f4 = lane & 3, sub = lane >> 2;
    int beg = rowptr[wid], end = rowptr[wid + 1];   // s_load (wid scalar)
    float dr = dinv[wid];                            // s_load
    float4 acc = make_float4(0.f, 0.f, 0.f, 0.f);
    for (int j = beg + sub; j < end; j += 16) {
        int c = colv[j];
        float4 hv = *reinterpret_cast<const float4*>(Hs + (size_t)c * HID + f4 * 4);
        acc.x += hv.x; acc.y += hv.y; acc.z += hv.z; acc.w += hv.w;
    }
#pragma unroll
    for (int d = 4; d < 64; d <<= 1) {
        acc.x += __shfl_xor(acc.x, d);
        acc.y += __shfl_xor(acc.y, d);
        acc.z += __shfl_xor(acc.z, d);
        acc.w += __shfl_xor(acc.w, d);
    }
    if (sub == 0) {
        float4 self = *reinterpret_cast<const float4*>(Hs + (size_t)wid * HID + f4 * 4);
        float4 bb = *reinterpret_cast<const float4*>(b1 + f4 * 4);
        float4 o;
        o.x = fmaxf((acc.x + self.x) * dr + bb.x, 0.f) * dr;
        o.y = fmaxf((acc.y + self.y) * dr + bb.y, 0.f) * dr;
        o.z = fmaxf((acc.z + self.z) * dr + bb.z, 0.f) * dr;
        o.w = fmaxf((acc.w + self.w) * dr + bb.w, 0.f) * dr;
        *reinterpret_cast<float4*>(h1s + (size_t)wid * HID + f4 * 4) = o;
    }
}

// -- agg2: wave/node pull of h1s (float4), fused 16x40 GEMM + bias -> out -----
__global__ __launch_bounds__(256) void k_agg2(const int* __restrict__ rowptr,
                                              const int* __restrict__ colv,
                                              const float* __restrict__ dinv,
                                              const float* __restrict__ h1s,
                                              const float* __restrict__ W2,
                                              const float* __restrict__ b2,
                                              float* __restrict__ out) {
    int wid = __builtin_amdgcn_readfirstlane((blockIdx.x * 256 + threadIdx.x) >> 6);
    if (wid >= N_NODES) return;
    int lane = threadIdx.x & 63;
    int f4 = lane & 3, sub = lane >> 2;
    int beg = rowptr[wid], end = rowptr[wid + 1];   // s_load
    float dr = dinv[wid];                            // s_load
    float4 acc = make_float4(0.f, 0.f, 0.f, 0.f);
    for (int j = beg + sub; j < end; j += 16) {
        int c = colv[j];
        float4 hv = *reinterpret_cast<const float4*>(h1s + (size_t)c * HID + f4 * 4);
        acc.x += hv.x; acc.y += hv.y; acc.z += hv.z; acc.w += hv.w;
    }
#pragma unroll
    for (int d = 4; d < 64; d <<= 1) {
        acc.x += __shfl_xor(acc.x, d);
        acc.y += __shfl_xor(acc.y, d);
        acc.z += __shfl_xor(acc.z, d);
        acc.w += __shfl_xor(acc.w, d);
    }
    float4 self = *reinterpret_cast<const float4*>(h1s + (size_t)wid * HID + f4 * 4);
    float4 w4;
    w4.x = (acc.x + self.x) * dr;
    w4.y = (acc.y + self.y) * dr;
    w4.z = (acc.z + self.z) * dr;
    w4.w = (acc.w + self.w) * dr;
    if (lane < F_OUT) {
        float o = b2[lane];
#pragma unroll
        for (int k = 0; k < HID; ++k) {
            float comp = (k & 3) == 0 ? w4.x : (k & 3) == 1 ? w4.y
                        : (k & 3) == 2 ? w4.z : w4.w;
            float wk = __shfl(comp, k >> 2);   // lane k>>2 holds f4 == k>>2
            o = fmaf(wk, W2[k * F_OUT + lane], o);
        }
        out[(size_t)wid * F_OUT + lane] = o;
    }
}

// ---------------- launch ----------------
extern "C" void kernel_launch(void* const* d_in, const int* in_sizes, int n_in,
                              void* d_out, int out_size, void* d_ws, size_t ws_size,
                              hipStream_t stream) {
    const float* x  = (const float*)d_in[0];
    const int* ei   = (const int*)d_in[1];      // int32 [2][E]
    const float* W1 = (const float*)d_in[2];
    const float* b1 = (const float*)d_in[3];
    const float* W2 = (const float*)d_in[4];
    const float* b2 = (const float*)d_in[5];
    float* out = (float*)d_out;
    const int E = in_sizes[1] / 2;

    // ws layout (4B units)
    int* gcursor          = (int*)d_ws;                      // 12544
    int* rowptr           = gcursor + 12544;                 // 100016
    float* dinv           = (float*)(rowptr + 100016);       // 100032
    int* colv             = (int*)(dinv + 100032);           // 3,200,000
    unsigned int* sortbuf = (unsigned int*)(colv + 3200000); // 3,612,672
    float* h1s            = (float*)sortbuf;                 // alias: dead after build
    float* Hs             = (float*)(sortbuf + 3612672);     // 1,600,000
    // total ~34.5 MB

    const int nbW = (N_NODES * 64 + 255) / 256;    // 25000 (wave per node)
    const int nbG = (N_NODES + 127) / 128;         // 782

    k_zero<<<(NB * CUR_PAD + 255) / 256, 256, 0, stream>>>(gcursor);
    k_fat<<<PARTB + nbG, 256, 0, stream>>>(x, W1, ei, E, gcursor, sortbuf, Hs);
    k_build<<<NB, 256, 0, stream>>>(sortbuf, gcursor, rowptr, dinv, colv, Hs);
    k_agg1<<<nbW, 256, 0, stream>>>(rowptr, colv, dinv, Hs, b1, h1s);
    k_agg2<<<nbW, 256, 0, stream>>>(rowptr, colv, dinv, h1s, W2, b2, out);
}

// Round 14
// 211.347 us; speedup vs baseline: 1.1644x; 1.1644x over previous
//
#include <hip/hip_runtime.h>

#define N_NODES 100000
#define F_IN 512
#define HID 16
#define F_OUT 40

#define NB 784        // buckets = row >> 7
#define BSHIFT 7
#define ROWS_PB 128
#define BCAP 4608     // mean 4096 + 8 sigma
#define CUR_PAD 16    // gcursor stride in ints (64B line per counter)
#define APAD 17
#define PARTB 512     // part1 blocks inside k_fat (512 threads each)
#define SROW 129      // stage buffer row stride in words (b32 conflict-free)

// ---------------- zero gcursor ----------------
__global__ void k_zero(int* __restrict__ g) {
    int i = blockIdx.x * 256 + threadIdx.x;
    if (i < NB * CUR_PAD) g[i] = 0;
}

// ---- FAT: blocks [0,PARTB) = edge bucket-scatter; rest = staged GEMM1 ------
__global__ __launch_bounds__(512) void k_fat(const float* __restrict__ x,
                                             const float* __restrict__ W1,
                                             const int* __restrict__ ei, int E,
                                             int* __restrict__ gcursor,
                                             unsigned int* __restrict__ sortbuf,
                                             float* __restrict__ Hs) {
    __shared__ float smem[8 * 64 * APAD];   // 34816 B: stage buf / red buf / part1
    int t = threadIdx.x;
    if (blockIdx.x < PARTB) {
        // ---------------- part1: bucket scatter (packed u32) ----------------
        int* lcnt = (int*)smem;         // NB
        int* gb   = lcnt + NB;          // NB
        int epb = (E + PARTB - 1) / PARTB;          // 6250
        int base = blockIdx.x * epb;
        int lim = min(base + epb, E);
        for (int cbase = base; cbase < lim; cbase += 4096) {
            int cend = min(cbase + 4096, lim);
            for (int i = t; i < NB; i += 512) lcnt[i] = 0;
            __syncthreads();
            unsigned int v[8]; int bkt[8], mi[8];
#pragma unroll
            for (int i = 0; i < 8; ++i) {
                int e = cbase + i * 512 + t;
                bkt[i] = -1;
                if (e < cend) {
                    int r = ei[e], c = ei[E + e];
                    bkt[i] = r >> BSHIFT;
                    v[i] = ((unsigned)(r & (ROWS_PB - 1)) << 17) | (unsigned)c;
                    mi[i] = atomicAdd(&lcnt[bkt[i]], 1);
                }
            }
            __syncthreads();
            for (int i = t; i < NB; i += 512)
                gb[i] = atomicAdd(&gcursor[i * CUR_PAD], lcnt[i]);
            __syncthreads();
#pragma unroll
            for (int i = 0; i < 8; ++i)
                if (bkt[i] >= 0) {
                    int idx = gb[bkt[i]] + mi[i];
                    if (idx < BCAP) sortbuf[(size_t)bkt[i] * BCAP + idx] = v[i];
                }
            __syncthreads();
        }
    } else {
        // -------- GEMM1: LDS-staged x tile, contiguous global reads ---------
        // 64 rows/block, 4 stages x 128k; thread = (row t&63, ksub t>>6).
        int bid = blockIdx.x - PARTB;
        int tilebase = bid * 64;
        int srow = t >> 5;            // staging: 16 rows per round, 2/wave
        int sseg = t & 31;            // 32 x float4 per row
        int crow = t & 63;            // compute row
        int ksub = __builtin_amdgcn_readfirstlane(t >> 6);   // 0..7 wave id

        float acc[HID];
#pragma unroll
        for (int f = 0; f < HID; ++f) acc[f] = 0.0f;

        // prologue: load stage 0 (4 rounds x float4/thread, contiguous/wave)
        float4 rg[4];
#pragma unroll
        for (int q = 0; q < 4; ++q) {
            int r = tilebase + q * 16 + srow;
            r = min(r, N_NODES - 1);
            rg[q] = *reinterpret_cast<const float4*>(x + (size_t)r * F_IN + sseg * 4);
        }
        for (int s = 0; s < 4; ++s) {
            __syncthreads();    // stage buffer free
#pragma unroll
            for (int q = 0; q < 4; ++q) {
                int base = (q * 16 + srow) * SROW + sseg * 4;
                smem[base + 0] = rg[q].x;
                smem[base + 1] = rg[q].y;
                smem[base + 2] = rg[q].z;
                smem[base + 3] = rg[q].w;
            }
            if (s < 3) {        // issue next stage's loads; land during compute
#pragma unroll
                for (int q = 0; q < 4; ++q) {
                    int r = tilebase + q * 16 + srow;
                    r = min(r, N_NODES - 1);
                    rg[q] = *reinterpret_cast<const float4*>(
                        x + (size_t)r * F_IN + (s + 1) * 128 + sseg * 4);
                }
            }
            __syncthreads();    // stage ready
            const float* wp = W1 + (s * 128 + ksub * 16) * HID;
            int lbase = crow * SROW + ksub * 16;
#pragma unroll
            for (int kk = 0; kk < 16; ++kk) {
                float xv = smem[lbase + kk];
#pragma unroll
                for (int f = 0; f < HID; ++f)
                    acc[f] = fmaf(xv, wp[kk * HID + f], acc[f]);  // s_load
            }
        }
        // ---- reduce 8 ksub partials per row via LDS (reuse buffer) ----
        __syncthreads();
        int rbase = (ksub * 64 + crow) * APAD;
#pragma unroll
        for (int f = 0; f < HID; ++f) smem[rbase + f] = acc[f];
        __syncthreads();
#pragma unroll
        for (int p = 0; p < 2; ++p) {
            int o = p * 512 + t;              // 0..1023 = 64 rows x 16 f
            int r = o >> 4, f = o & 15;
            int rgl = tilebase + r;
            if (rgl < N_NODES) {
                float sum = 0.0f;
#pragma unroll
                for (int c = 0; c < 8; ++c) sum += smem[(c * 64 + r) * APAD + f];
                Hs[(size_t)rgl * HID + f] = sum;   // raw; scaled in k_build
            }
        }
    }
}

// -- build: bucket scan + LDS hist + scatter; fused dinv + Hs scaling ---------
__global__ __launch_bounds__(256) void k_build(const unsigned int* __restrict__ sortbuf,
                                               const int* __restrict__ gcursor,
                                               int* __restrict__ rowptr,
                                               float* __restrict__ dinv,
                                               int* __restrict__ colv,
                                               float* __restrict__ Hs) {
    __shared__ int bb[NB];
    __shared__ int s[256];
    __shared__ int hist[ROWS_PB];
    __shared__ int rstart[ROWS_PB];
    __shared__ int cur[ROWS_PB];
    __shared__ float sdinv[ROWS_PB];
    int b = blockIdx.x, t = threadIdx.x;

    int l0 = 0, l1 = 0, l2 = 0, l3 = 0;
    if (t < 196) {
        l0 = min(gcursor[(t * 4 + 0) * CUR_PAD], BCAP);
        l1 = min(gcursor[(t * 4 + 1) * CUR_PAD], BCAP);
        l2 = min(gcursor[(t * 4 + 2) * CUR_PAD], BCAP);
        l3 = min(gcursor[(t * 4 + 3) * CUR_PAD], BCAP);
    }
    int part = l0 + l1 + l2 + l3;
    s[t] = part;
    __syncthreads();
    for (int off = 1; off < 256; off <<= 1) {
        int a = (t >= off) ? s[t - off] : 0;
        __syncthreads();
        s[t] += a;
        __syncthreads();
    }
    if (t < 196) {
        int ex = s[t] - part;
        bb[t * 4 + 0] = ex;
        bb[t * 4 + 1] = ex + l0;
        bb[t * 4 + 2] = ex + l0 + l1;
        bb[t * 4 + 3] = ex + l0 + l1 + l2;
    }
    if (t < ROWS_PB) hist[t] = 0;
    __syncthreads();
    int gbase = bb[b];
    int n = min(gcursor[b * CUR_PAD], BCAP);
    if (b == 0 && t == 0) rowptr[N_NODES] = s[255];

    const unsigned int* sb = sortbuf + (size_t)b * BCAP;
    for (int i = t; i < n; i += 256) atomicAdd(&hist[sb[i] >> 17], 1);
    __syncthreads();
    int c0 = (t < ROWS_PB) ? hist[t] : 0;
    s[t] = c0;
    __syncthreads();
    for (int off = 1; off < 256; off <<= 1) {
        int a = (t >= off) ? s[t - off] : 0;
        __syncthreads();
        s[t] += a;
        __syncthreads();
    }
    if (t < ROWS_PB) {
        int ex = s[t] - c0;
        rstart[t] = ex;
        cur[t] = 0;
        float dv = rsqrtf((float)(c0 + 1));   // +1 self-loop
        sdinv[t] = dv;
        int g = b * ROWS_PB + t;
        if (g < N_NODES) {
            rowptr[g] = gbase + ex;
            dinv[g] = dv;
        }
    }
    __syncthreads();
    for (int i = t; i < n; i += 256) {
        unsigned int v = sb[i];
        int lr = v >> 17;
        int pos = atomicAdd(&cur[lr], 1);
        colv[gbase + rstart[lr] + pos] = (int)(v & 0x1FFFFu);
    }
    __syncthreads();
    for (int i = t; i < ROWS_PB * 4; i += 256) {
        int row = i >> 2, q = i & 3;
        int g = b * ROWS_PB + row;
        if (g < N_NODES) {
            float4* p = reinterpret_cast<float4*>(Hs + (size_t)g * HID + q * 4);
            float4 vv = *p;
            float dv = sdinv[row];
            vv.x *= dv; vv.y *= dv; vv.z *= dv; vv.w *= dv;
            *p = vv;
        }
    }
}

// -- agg1: wave/node pull, float4 gathers, scalar-hoisted row meta ------------
__global__ __launch_bounds__(256) void k_agg1(const int* __restrict__ rowptr,
                                              const int* __restrict__ colv,
                                              const float* __restrict__ dinv,
                                              const float* __restrict__ Hs,
                                              const float* __restrict__ b1,
                                              float* __restrict__ h1s) {
    int wid = __builtin_amdgcn_readfirstlane((blockIdx.x * 256 + threadIdx.x) >> 6);
    if (wid >= N_NODES) return;
    int lane = threadIdx.x & 63;
    int f4 = lane & 3, sub = lane >> 2;
    int beg = rowptr[wid], end = rowptr[wid + 1];   // s_load (wid scalar)
    float dr = dinv[wid];                            // s_load
    float4 acc = make_float4(0.f, 0.f, 0.f, 0.f);
    for (int j = beg + sub; j < end; j += 16) {
        int c = colv[j];
        float4 hv = *reinterpret_cast<const float4*>(Hs + (size_t)c * HID + f4 * 4);
        acc.x += hv.x; acc.y += hv.y; acc.z += hv.z; acc.w += hv.w;
    }
#pragma unroll
    for (int d = 4; d < 64; d <<= 1) {
        acc.x += __shfl_xor(acc.x, d);
        acc.y += __shfl_xor(acc.y, d);
        acc.z += __shfl_xor(acc.z, d);
        acc.w += __shfl_xor(acc.w, d);
    }
    if (sub == 0) {
        float4 self = *reinterpret_cast<const float4*>(Hs + (size_t)wid * HID + f4 * 4);
        float4 bb = *reinterpret_cast<const float4*>(b1 + f4 * 4);
        float4 o;
        o.x = fmaxf((acc.x + self.x) * dr + bb.x, 0.f) * dr;
        o.y = fmaxf((acc.y + self.y) * dr + bb.y, 0.f) * dr;
        o.z = fmaxf((acc.z + self.z) * dr + bb.z, 0.f) * dr;
        o.w = fmaxf((acc.w + self.w) * dr + bb.w, 0.f) * dr;
        *reinterpret_cast<float4*>(h1s + (size_t)wid * HID + f4 * 4) = o;
    }
}

// -- agg2: wave/node pull of h1s (float4), fused 16x40 GEMM + bias -> out -----
__global__ __launch_bounds__(256) void k_agg2(const int* __restrict__ rowptr,
                                              const int* __restrict__ colv,
                                              const float* __restrict__ dinv,
                                              const float* __restrict__ h1s,
                                              const float* __restrict__ W2,
                                              const float* __restrict__ b2,
                                              float* __restrict__ out) {
    int wid = __builtin_amdgcn_readfirstlane((blockIdx.x * 256 + threadIdx.x) >> 6);
    if (wid >= N_NODES) return;
    int lane = threadIdx.x & 63;
    int f4 = lane & 3, sub = lane >> 2;
    int beg = rowptr[wid], end = rowptr[wid + 1];   // s_load
    float dr = dinv[wid];                            // s_load
    float4 acc = make_float4(0.f, 0.f, 0.f, 0.f);
    for (int j = beg + sub; j < end; j += 16) {
        int c = colv[j];
        float4 hv = *reinterpret_cast<const float4*>(h1s + (size_t)c * HID + f4 * 4);
        acc.x += hv.x; acc.y += hv.y; acc.z += hv.z; acc.w += hv.w;
    }
#pragma unroll
    for (int d = 4; d < 64; d <<= 1) {
        acc.x += __shfl_xor(acc.x, d);
        acc.y += __shfl_xor(acc.y, d);
        acc.z += __shfl_xor(acc.z, d);
        acc.w += __shfl_xor(acc.w, d);
    }
    float4 self = *reinterpret_cast<const float4*>(h1s + (size_t)wid * HID + f4 * 4);
    float4 w4;
    w4.x = (acc.x + self.x) * dr;
    w4.y = (acc.y + self.y) * dr;
    w4.z = (acc.z + self.z) * dr;
    w4.w = (acc.w + self.w) * dr;
    if (lane < F_OUT) {
        float o = b2[lane];
#pragma unroll
        for (int k = 0; k < HID; ++k) {
            float comp = (k & 3) == 0 ? w4.x : (k & 3) == 1 ? w4.y
                        : (k & 3) == 2 ? w4.z : w4.w;
            float wk = __shfl(comp, k >> 2);   // lane k>>2 holds f4 == k>>2
            o = fmaf(wk, W2[k * F_OUT + lane], o);
        }
        out[(size_t)wid * F_OUT + lane] = o;
    }
}

// ---------------- launch ----------------
extern "C" void kernel_launch(void* const* d_in, const int* in_sizes, int n_in,
                              void* d_out, int out_size, void* d_ws, size_t ws_size,
                              hipStream_t stream) {
    const float* x  = (const float*)d_in[0];
    const int* ei   = (const int*)d_in[1];      // int32 [2][E]
    const float* W1 = (const float*)d_in[2];
    const float* b1 = (const float*)d_in[3];
    const float* W2 = (const float*)d_in[4];
    const float* b2 = (const float*)d_in[5];
    float* out = (float*)d_out;
    const int E = in_sizes[1] / 2;

    // ws layout (4B units)
    int* gcursor          = (int*)d_ws;                      // 12544
    int* rowptr           = gcursor + 12544;                 // 100016
    float* dinv           = (float*)(rowptr + 100016);       // 100032
    int* colv             = (int*)(dinv + 100032);           // 3,200,000
    unsigned int* sortbuf = (unsigned int*)(colv + 3200000); // 3,612,672
    float* h1s            = (float*)sortbuf;                 // alias: dead after build
    float* Hs             = (float*)(sortbuf + 3612672);     // 1,600,000
    // total ~34.5 MB

    const int nbW = (N_NODES * 64 + 255) / 256;    // 25000 (wave per node)
    const int nbG = (N_NODES + 63) / 64;           // 1563

    k_zero<<<(NB * CUR_PAD + 255) / 256, 256, 0, stream>>>(gcursor);
    k_fat<<<PARTB + nbG, 512, 0, stream>>>(x, W1, ei, E, gcursor, sortbuf, Hs);
    k_build<<<NB, 256, 0, stream>>>(sortbuf, gcursor, rowptr, dinv, colv, Hs);
    k_agg1<<<nbW, 256, 0, stream>>>(rowptr, colv, dinv, Hs, b1, h1s);
    k_agg2<<<nbW, 256, 0, stream>>>(rowptr, colv, dinv, h1s, W2, b2, out);
}

// Round 15
// 211.145 us; speedup vs baseline: 1.1655x; 1.0010x over previous
//
#include <hip/hip_runtime.h>

#define N_NODES 100000
#define F_IN 512
#define HID 16
#define F_OUT 40

#define NB 784        // buckets = row >> 7
#define BSHIFT 7
#define ROWS_PB 128
#define BCAP 4608     // mean 4096 + 8 sigma
#define CUR_PAD 16    // gcursor stride in ints (64B line per counter)
#define APAD 17
#define PARTB 512     // part1 blocks inside k_fat (512 threads each)
#define SROW 129      // stage buffer row stride in words (b32 conflict-free)

// ---------------- zero gcursor ----------------
__global__ void k_zero(int* __restrict__ g) {
    int i = blockIdx.x * 256 + threadIdx.x;
    if (i < NB * CUR_PAD) g[i] = 0;
}

// ---- FAT: blocks [0,PARTB) = edge bucket-scatter; rest = staged GEMM1 ------
__global__ __launch_bounds__(512) void k_fat(const float* __restrict__ x,
                                             const float* __restrict__ W1,
                                             const int* __restrict__ ei, int E,
                                             int* __restrict__ gcursor,
                                             unsigned int* __restrict__ sortbuf,
                                             float* __restrict__ Hs) {
    __shared__ float smem[8 * 64 * APAD];   // 34816 B: stage buf / red buf / part1
    int t = threadIdx.x;
    if (blockIdx.x < PARTB) {
        // ---------------- part1: bucket scatter (packed u32) ----------------
        int* lcnt = (int*)smem;         // NB
        int* gb   = lcnt + NB;          // NB
        int epb = (E + PARTB - 1) / PARTB;          // 6250
        int base = blockIdx.x * epb;
        int lim = min(base + epb, E);
        for (int cbase = base; cbase < lim; cbase += 4096) {
            int cend = min(cbase + 4096, lim);
            for (int i = t; i < NB; i += 512) lcnt[i] = 0;
            __syncthreads();
            unsigned int v[8]; int bkt[8], mi[8];
#pragma unroll
            for (int i = 0; i < 8; ++i) {
                int e = cbase + i * 512 + t;
                bkt[i] = -1;
                if (e < cend) {
                    int r = ei[e], c = ei[E + e];
                    bkt[i] = r >> BSHIFT;
                    v[i] = ((unsigned)(r & (ROWS_PB - 1)) << 17) | (unsigned)c;
                    mi[i] = atomicAdd(&lcnt[bkt[i]], 1);
                }
            }
            __syncthreads();
            for (int i = t; i < NB; i += 512)
                gb[i] = atomicAdd(&gcursor[i * CUR_PAD], lcnt[i]);
            __syncthreads();
#pragma unroll
            for (int i = 0; i < 8; ++i)
                if (bkt[i] >= 0) {
                    int idx = gb[bkt[i]] + mi[i];
                    if (idx < BCAP) sortbuf[(size_t)bkt[i] * BCAP + idx] = v[i];
                }
            __syncthreads();
        }
    } else {
        // -------- GEMM1: LDS-staged x tile, contiguous global reads ---------
        // 64 rows/block, 4 stages x 128k; thread = (row t&63, ksub t>>6).
        // T14 ordering: prefetch issued AFTER the ready-barrier so the
        // barrier's vmcnt(0) drain doesn't serialize load->compute.
        int bid = blockIdx.x - PARTB;
        int tilebase = bid * 64;
        int srow = t >> 5;            // staging: 16 rows per round, 2/wave
        int sseg = t & 31;            // 32 x float4 per row
        int crow = t & 63;            // compute row
        int ksub = __builtin_amdgcn_readfirstlane(t >> 6);   // 0..7 wave id

        float acc[HID];
#pragma unroll
        for (int f = 0; f < HID; ++f) acc[f] = 0.0f;

        // prologue: load stage 0 (4 x float4/thread, contiguous per wave)
        float4 rg[4];
#pragma unroll
        for (int q = 0; q < 4; ++q) {
            int r = tilebase + q * 16 + srow;
            r = min(r, N_NODES - 1);
            rg[q] = *reinterpret_cast<const float4*>(x + (size_t)r * F_IN + sseg * 4);
        }
        for (int s = 0; s < 4; ++s) {
            __syncthreads();    // stage buffer free (drains prev prefetch: landed)
#pragma unroll
            for (int q = 0; q < 4; ++q) {
                int base = (q * 16 + srow) * SROW + sseg * 4;
                smem[base + 0] = rg[q].x;
                smem[base + 1] = rg[q].y;
                smem[base + 2] = rg[q].z;
                smem[base + 3] = rg[q].w;
            }
            __syncthreads();    // stage ready (vmcnt already 0 here: cheap drain)
            if (s < 3) {        // issue next stage NOW -> flies during compute
#pragma unroll
                for (int q = 0; q < 4; ++q) {
                    int r = tilebase + q * 16 + srow;
                    r = min(r, N_NODES - 1);
                    rg[q] = *reinterpret_cast<const float4*>(
                        x + (size_t)r * F_IN + (s + 1) * 128 + sseg * 4);
                }
            }
            const float* wp = W1 + (s * 128 + ksub * 16) * HID;
            int lbase = crow * SROW + ksub * 16;
#pragma unroll
            for (int kk = 0; kk < 16; ++kk) {
                float xv = smem[lbase + kk];
#pragma unroll
                for (int f = 0; f < HID; ++f)
                    acc[f] = fmaf(xv, wp[kk * HID + f], acc[f]);  // s_load
            }
        }
        // ---- reduce 8 ksub partials per row via LDS (reuse buffer) ----
        __syncthreads();
        int rbase = (ksub * 64 + crow) * APAD;
#pragma unroll
        for (int f = 0; f < HID; ++f) smem[rbase + f] = acc[f];
        __syncthreads();
#pragma unroll
        for (int p = 0; p < 2; ++p) {
            int o = p * 512 + t;              // 0..1023 = 64 rows x 16 f
            int r = o >> 4, f = o & 15;
            int rgl = tilebase + r;
            if (rgl < N_NODES) {
                float sum = 0.0f;
#pragma unroll
                for (int c = 0; c < 8; ++c) sum += smem[(c * 64 + r) * APAD + f];
                Hs[(size_t)rgl * HID + f] = sum;   // raw; scaled in k_build
            }
        }
    }
}

// -- build: bucket scan + LDS hist + scatter; fused dinv + Hs scaling ---------
__global__ __launch_bounds__(256) void k_build(const unsigned int* __restrict__ sortbuf,
                                               const int* __restrict__ gcursor,
                                               int* __restrict__ rowptr,
                                               float* __restrict__ dinv,
                                               int* __restrict__ colv,
                                               float* __restrict__ Hs) {
    __shared__ int bb[NB];
    __shared__ int s[256];
    __shared__ int hist[ROWS_PB];
    __shared__ int rstart[ROWS_PB];
    __shared__ int cur[ROWS_PB];
    __shared__ float sdinv[ROWS_PB];
    int b = blockIdx.x, t = threadIdx.x;

    int l0 = 0, l1 = 0, l2 = 0, l3 = 0;
    if (t < 196) {
        l0 = min(gcursor[(t * 4 + 0) * CUR_PAD], BCAP);
        l1 = min(gcursor[(t * 4 + 1) * CUR_PAD], BCAP);
        l2 = min(gcursor[(t * 4 + 2) * CUR_PAD], BCAP);
        l3 = min(gcursor[(t * 4 + 3) * CUR_PAD], BCAP);
    }
    int part = l0 + l1 + l2 + l3;
    s[t] = part;
    __syncthreads();
    for (int off = 1; off < 256; off <<= 1) {
        int a = (t >= off) ? s[t - off] : 0;
        __syncthreads();
        s[t] += a;
        __syncthreads();
    }
    if (t < 196) {
        int ex = s[t] - part;
        bb[t * 4 + 0] = ex;
        bb[t * 4 + 1] = ex + l0;
        bb[t * 4 + 2] = ex + l0 + l1;
        bb[t * 4 + 3] = ex + l0 + l1 + l2;
    }
    if (t < ROWS_PB) hist[t] = 0;
    __syncthreads();
    int gbase = bb[b];
    int n = min(gcursor[b * CUR_PAD], BCAP);
    if (b == 0 && t == 0) rowptr[N_NODES] = s[255];

    const unsigned int* sb = sortbuf + (size_t)b * BCAP;
    for (int i = t; i < n; i += 256) atomicAdd(&hist[sb[i] >> 17], 1);
    __syncthreads();
    int c0 = (t < ROWS_PB) ? hist[t] : 0;
    s[t] = c0;
    __syncthreads();
    for (int off = 1; off < 256; off <<= 1) {
        int a = (t >= off) ? s[t - off] : 0;
        __syncthreads();
        s[t] += a;
        __syncthreads();
    }
    if (t < ROWS_PB) {
        int ex = s[t] - c0;
        rstart[t] = ex;
        cur[t] = 0;
        float dv = rsqrtf((float)(c0 + 1));   // +1 self-loop
        sdinv[t] = dv;
        int g = b * ROWS_PB + t;
        if (g < N_NODES) {
            rowptr[g] = gbase + ex;
            dinv[g] = dv;
        }
    }
    __syncthreads();
    for (int i = t; i < n; i += 256) {
        unsigned int v = sb[i];
        int lr = v >> 17;
        int pos = atomicAdd(&cur[lr], 1);
        colv[gbase + rstart[lr] + pos] = (int)(v & 0x1FFFFu);
    }
    __syncthreads();
    for (int i = t; i < ROWS_PB * 4; i += 256) {
        int row = i >> 2, q = i & 3;
        int g = b * ROWS_PB + row;
        if (g < N_NODES) {
            float4* p = reinterpret_cast<float4*>(Hs + (size_t)g * HID + q * 4);
            float4 vv = *p;
            float dv = sdinv[row];
            vv.x *= dv; vv.y *= dv; vv.z *= dv; vv.w *= dv;
            *p = vv;
        }
    }
}

// -- agg1: wave/node pull, float4 gathers, scalar-hoisted row meta ------------
__global__ __launch_bounds__(256) void k_agg1(const int* __restrict__ rowptr,
                                              const int* __restrict__ colv,
                                              const float* __restrict__ dinv,
                                              const float* __restrict__ Hs,
                                              const float* __restrict__ b1,
                                              float* __restrict__ h1s) {
    int wid = __builtin_amdgcn_readfirstlane((blockIdx.x * 256 + threadIdx.x) >> 6);
    if (wid >= N_NODES) return;
    int lane = threadIdx.x & 63;
    int f4 = lane & 3, sub = lane >> 2;
    int beg = rowptr[wid], end = rowptr[wid + 1];   // s_load (wid scalar)
    float dr = dinv[wid];                            // s_load
    float4 acc = make_float4(0.f, 0.f, 0.f, 0.f);
    for (int j = beg + sub; j < end; j += 16) {
        int c = colv[j];
        float4 hv = *reinterpret_cast<const float4*>(Hs + (size_t)c * HID + f4 * 4);
        acc.x += hv.x; acc.y += hv.y; acc.z += hv.z; acc.w += hv.w;
    }
#pragma unroll
    for (int d = 4; d < 64; d <<= 1) {
        acc.x += __shfl_xor(acc.x, d);
        acc.y += __shfl_xor(acc.y, d);
        acc.z += __shfl_xor(acc.z, d);
        acc.w += __shfl_xor(acc.w, d);
    }
    if (sub == 0) {
        float4 self = *reinterpret_cast<const float4*>(Hs + (size_t)wid * HID + f4 * 4);
        float4 bb = *reinterpret_cast<const float4*>(b1 + f4 * 4);
        float4 o;
        o.x = fmaxf((acc.x + self.x) * dr + bb.x, 0.f) * dr;
        o.y = fmaxf((acc.y + self.y) * dr + bb.y, 0.f) * dr;
        o.z = fmaxf((acc.z + self.z) * dr + bb.z, 0.f) * dr;
        o.w = fmaxf((acc.w + self.w) * dr + bb.w, 0.f) * dr;
        *reinterpret_cast<float4*>(h1s + (size_t)wid * HID + f4 * 4) = o;
    }
}

// -- agg2: wave/node pull of h1s (float4), fused 16x40 GEMM + bias -> out -----
__global__ __launch_bounds__(256) void k_agg2(const int* __restrict__ rowptr,
                                              const int* __restrict__ colv,
                                              const float* __restrict__ dinv,
                                              const float* __restrict__ h1s,
                                              const float* __restrict__ W2,
                                              const float* __restrict__ b2,
                                              float* __restrict__ out) {
    int wid = __builtin_amdgcn_readfirstlane((blockIdx.x * 256 + threadIdx.x) >> 6);
    if (wid >= N_NODES) return;
    int lane = threadIdx.x & 63;
    int f4 = lane & 3, sub = lane >> 2;
    int beg = rowptr[wid], end = rowptr[wid + 1];   // s_load
    float dr = dinv[wid];                            // s_load
    float4 acc = make_float4(0.f, 0.f, 0.f, 0.f);
    for (int j = beg + sub; j < end; j += 16) {
        int c = colv[j];
        float4 hv = *reinterpret_cast<const float4*>(h1s + (size_t)c * HID + f4 * 4);
        acc.x += hv.x; acc.y += hv.y; acc.z += hv.z; acc.w += hv.w;
    }
#pragma unroll
    for (int d = 4; d < 64; d <<= 1) {
        acc.x += __shfl_xor(acc.x, d);
        acc.y += __shfl_xor(acc.y, d);
        acc.z += __shfl_xor(acc.z, d);
        acc.w += __shfl_xor(acc.w, d);
    }
    float4 self = *reinterpret_cast<const float4*>(h1s + (size_t)wid * HID + f4 * 4);
    float4 w4;
    w4.x = (acc.x + self.x) * dr;
    w4.y = (acc.y + self.y) * dr;
    w4.z = (acc.z + self.z) * dr;
    w4.w = (acc.w + self.w) * dr;
    if (lane < F_OUT) {
        float o = b2[lane];
#pragma unroll
        for (int k = 0; k < HID; ++k) {
            float comp = (k & 3) == 0 ? w4.x : (k & 3) == 1 ? w4.y
                        : (k & 3) == 2 ? w4.z : w4.w;
            float wk = __shfl(comp, k >> 2);   // lane k>>2 holds f4 == k>>2
            o = fmaf(wk, W2[k * F_OUT + lane], o);
        }
        out[(size_t)wid * F_OUT + lane] = o;
    }
}

// ---------------- launch ----------------
extern "C" void kernel_launch(void* const* d_in, const int* in_sizes, int n_in,
                              void* d_out, int out_size, void* d_ws, size_t ws_size,
                              hipStream_t stream) {
    const float* x  = (const float*)d_in[0];
    const int* ei   = (const int*)d_in[1];      // int32 [2][E]
    const float* W1 = (const float*)d_in[2];
    const float* b1 = (const float*)d_in[3];
    const float* W2 = (const float*)d_in[4];
    const float* b2 = (const float*)d_in[5];
    float* out = (float*)d_out;
    const int E = in_sizes[1] / 2;

    // ws layout (4B units)
    int* gcursor          = (int*)d_ws;                      // 12544
    int* rowptr           = gcursor + 12544;                 // 100016
    float* dinv           = (float*)(rowptr + 100016);       // 100032
    int* colv             = (int*)(dinv + 100032);           // 3,200,000
    unsigned int* sortbuf = (unsigned int*)(colv + 3200000); // 3,612,672
    float* h1s            = (float*)sortbuf;                 // alias: dead after build
    float* Hs             = (float*)(sortbuf + 3612672);     // 1,600,000
    // total ~34.5 MB

    const int nbW = (N_NODES * 64 + 255) / 256;    // 25000 (wave per node)
    const int nbG = (N_NODES + 63) / 64;           // 1563

    k_zero<<<(NB * CUR_PAD + 255) / 256, 256, 0, stream>>>(gcursor);
    k_fat<<<PARTB + nbG, 512, 0, stream>>>(x, W1, ei, E, gcursor, sortbuf, Hs);
    k_build<<<NB, 256, 0, stream>>>(sortbuf, gcursor, rowptr, dinv, colv, Hs);
    k_agg1<<<nbW, 256, 0, stream>>>(rowptr, colv, dinv, Hs, b1, h1s);
    k_agg2<<<nbW, 256, 0, stream>>>(rowptr, colv, dinv, h1s, W2, b2, out);
}